// Round 7
// baseline (205.100 us; speedup 1.0000x reference)
//
#include <hip/hip_runtime.h>
#include <math.h>

typedef __attribute__((ext_vector_type(8))) short bf16x8;
typedef __attribute__((ext_vector_type(4))) float f32x4;

constexpr int D = 256;           // feature dim (K of GEMM)
constexpr int H = 128;           // hidden dim
constexpr int KSTEPS = D / 32;   // 8 MFMA k-steps
constexpr int BM = 64;           // rows per block

__device__ __forceinline__ float trunc_bf(float a) {
  return __uint_as_float(__float_as_uint(a) & 0xFFFF0000u);
}
__device__ __forceinline__ unsigned int pack2_bf(float a, float b) {
  return (__float_as_uint(a) >> 16) | (__float_as_uint(b) & 0xFFFF0000u);
}

union FragU { uint4 u; bf16x8 f; };

// ---- init: zero d_out + Z accumulator --------------------------------------
extern "C" __global__ void __launch_bounds__(256)
k_init(float* __restrict__ out, int out_size, float* __restrict__ zacc)
{
  const int i = blockIdx.x * 256 + threadIdx.x;
  if (i < out_size) out[i] = 0.0f;
  if (i == 0) *zacc = 0.0f;
}

// ---- Pre-pack W1 into per-lane MFMA B-fragment order (hi/lo bf16) ----------
extern "C" __global__ void __launch_bounds__(256)
k_pack(const float* __restrict__ W1, uint4* __restrict__ phi,
       uint4* __restrict__ plo)
{
  const int g = blockIdx.x * 256 + threadIdx.x;       // 0..4095
  const int c = g >> 9, ht = (g >> 6) & 7, l = g & 63;
  const int kbase = c * 32 + (l >> 4) * 8;
  const int col = ht * 16 + (l & 15);
  float v[8], lo[8];
#pragma unroll
  for (int i = 0; i < 8; ++i) {
    v[i] = W1[(size_t)(kbase + i) * H + col];
    lo[i] = v[i] - trunc_bf(v[i]);
  }
  uint4 h4, l4;
  h4.x = pack2_bf(v[0], v[1]); h4.y = pack2_bf(v[2], v[3]);
  h4.z = pack2_bf(v[4], v[5]); h4.w = pack2_bf(v[6], v[7]);
  l4.x = pack2_bf(lo[0], lo[1]); l4.y = pack2_bf(lo[2], lo[3]);
  l4.z = pack2_bf(lo[4], lo[5]); l4.w = pack2_bf(lo[6], lo[7]);
  phi[g] = h4; plo[g] = l4;
}

// LDS x-tile layout: plane(c,g) = 2 KB (g = 16-row stripe). Within a plane:
// 64 hi slots of 16 B (bytes 0..1023) then 64 lo slots (bytes 1024..2047).
// slot(l16,c) = lg*16 + (r15 ^ ((lg + 2c) & 15))  with lg=l16>>4, r15=l16&15.
// Writes (ds_write_b64) measure 2-way bank aliasing (free); reads are full-
// coverage ds_read_b128.
__device__ __forceinline__ int slot_of(int lg, int r15, int c) {
  return lg * 16 + (r15 ^ ((lg + 2 * c) & 15));
}

// ---- Fused: scores (MFMA) -> w = exp(s) -> weighted pool of own rows -------
// BM=64 rows. Staging: one global_load_dwordx4 per ROW per wave = 1 KB fully
// contiguous per instruction (HBM page-friendly). Full-K tile resident in
// LDS (64 KB) as hi/lo bf16 A-fragments -> k-loop has NO barriers.
// 4 waves (2x2): wave (rg,cg) computes rows rg*32..+32 x cols cg*64..+64.
extern "C" __global__ void __launch_bounds__(256, 2)
k_fused2(const float* __restrict__ x, const int* __restrict__ batch,
         const uint4* __restrict__ phi, const uint4* __restrict__ plo,
         const float* __restrict__ b1, const float* __restrict__ W2,
         const float* __restrict__ b2, float* __restrict__ out,
         float* __restrict__ zacc, int N)
{
  __shared__ char xlds[KSTEPS * 4 * 2048];   // 64 KB
  __shared__ float sred[2][BM];
  __shared__ float wlds[BM];

  const int t = threadIdx.x;
  const int l = t & 63;
  const int w = t >> 6;
  const int lg = l >> 4;      // k-group (read side)
  const int lr = l & 15;      // M-row (A) / N-col (B,C)
  const int rg = w >> 1;      // row half (0..1)
  const int cg = w & 1;       // col half (0..1)
  const int n0 = blockIdx.x * BM;

  // ---- stage: wave w loads rows w*16..w*16+15, packs hi/lo, transposes to LDS
  {
    const int wc = l >> 3;          // write-side kstep (cols 4l..4l+3)
    const int wlg = (l >> 1) & 3;   // write-side k-group
    const int wp = l & 1;           // write-side pair
#pragma unroll
    for (int i = 0; i < 16; ++i) {
      const int row = w * 16 + i;                       // block-local 0..63
      const int srow = min(n0 + row, N - 1);            // clamp (discarded)
      const float4 v = *reinterpret_cast<const float4*>(x + (size_t)srow * D + l * 4);
      uint2 hi, lo;
      hi.x = pack2_bf(v.x, v.y);
      hi.y = pack2_bf(v.z, v.w);
      lo.x = pack2_bf(v.x - trunc_bf(v.x), v.y - trunc_bf(v.y));
      lo.y = pack2_bf(v.z - trunc_bf(v.z), v.w - trunc_bf(v.w));
      const int sl = slot_of(wlg, row & 15, wc);
      char* pb = xlds + (wc * 4 + (row >> 4)) * 2048 + sl * 16 + wp * 8;
      *reinterpret_cast<uint2*>(pb) = hi;               // ds_write_b64
      *reinterpret_cast<uint2*>(pb + 1024) = lo;
    }
  }

  // B fragments for kstep 0 (overlaps staging; L2-resident after block 0)
  FragU bhi[4], blo[4], nbhi[4], nblo[4];
#pragma unroll
  for (int h = 0; h < 4; ++h) {
    const int ht = cg * 4 + h;
    bhi[h].u = phi[(0 * 8 + ht) * 64 + l];
    blo[h].u = plo[(0 * 8 + ht) * 64 + l];
  }
  __syncthreads();   // all ds_writes visible; tile is read-only from here

  f32x4 acc[2][4] = {};   // [stripe s (16 rows)][local htile h]

#pragma unroll 1
  for (int c = 0; c < KSTEPS; ++c) {
    if (c + 1 < KSTEPS) {
#pragma unroll
      for (int h = 0; h < 4; ++h) {
        const int ht = cg * 4 + h;
        nbhi[h].u = phi[((c + 1) * 8 + ht) * 64 + l];
        nblo[h].u = plo[((c + 1) * 8 + ht) * 64 + l];
      }
    }
    const int sl = slot_of(lg, lr, c);
#pragma unroll
    for (int s = 0; s < 2; ++s) {
      const int g = rg * 2 + s;
      const char* pb = xlds + (c * 4 + g) * 2048 + sl * 16;
      FragU ahi, alo;
      ahi.f = *reinterpret_cast<const bf16x8*>(pb);          // ds_read_b128
      alo.f = *reinterpret_cast<const bf16x8*>(pb + 1024);
#pragma unroll
      for (int h = 0; h < 4; ++h) {
        acc[s][h] = __builtin_amdgcn_mfma_f32_16x16x32_bf16(ahi.f, bhi[h].f, acc[s][h], 0, 0, 0);
        acc[s][h] = __builtin_amdgcn_mfma_f32_16x16x32_bf16(ahi.f, blo[h].f, acc[s][h], 0, 0, 0);
        acc[s][h] = __builtin_amdgcn_mfma_f32_16x16x32_bf16(alo.f, bhi[h].f, acc[s][h], 0, 0, 0);
      }
    }
#pragma unroll
    for (int h = 0; h < 4; ++h) { bhi[h] = nbhi[h]; blo[h] = nblo[h]; }
  }

  // ---- epilogue: relu(h+b1)@W2 partials, cross-wave sum, w=exp(s) ----------
  float bvv[4], wvv[4];
#pragma unroll
  for (int h = 0; h < 4; ++h) {
    const int col = (cg * 4 + h) * 16 + lr;
    bvv[h] = b1[col];
    wvv[h] = W2[col];
  }
#pragma unroll
  for (int s = 0; s < 2; ++s) {
#pragma unroll
    for (int r = 0; r < 4; ++r) {
      float p = 0.0f;
#pragma unroll
      for (int h = 0; h < 4; ++h)
        p = fmaf(fmaxf(acc[s][h][r] + bvv[h], 0.0f), wvv[h], p);
#pragma unroll
      for (int off = 1; off < 16; off <<= 1) p += __shfl_xor(p, off, 64);
      if (lr == 0) sred[cg][rg * 32 + s * 16 + lg * 4 + r] = p;
    }
  }
  __syncthreads();
  if (cg == 0) {                      // waves 0 and 2 finalize 32 rows each
    const int row = rg * 32 + (l & 31);
    const int node = n0 + row;
    const float sc = sred[0][row] + sred[1][row] + b2[0];
    const float wgt = (l < 32 && node < N) ? __expf(sc) : 0.0f;
    if (l < 32) wlds[row] = wgt;
    float zs = wgt;
#pragma unroll
    for (int off = 1; off < 64; off <<= 1) zs += __shfl_xor(zs, off, 64);
    if (l == 0) atomicAdd(zacc, zs);
  }
  __syncthreads();

  // ---- phase 2: pool own rows (batch sorted); lane owns 4 columns ---------
  {
    const int nStart = n0 + w * 16;
    const int nEnd = min(nStart + 16, N);
    if (nStart < nEnd) {
      float4 a4 = make_float4(0.f, 0.f, 0.f, 0.f);
      int bprev = batch[nStart];
      for (int n = nStart; n < nEnd; ++n) {
        const int b = batch[n];
        if (b != bprev) {
          float* o = out + (size_t)bprev * D + l * 4;
          atomicAdd(o + 0, a4.x); atomicAdd(o + 1, a4.y);
          atomicAdd(o + 2, a4.z); atomicAdd(o + 3, a4.w);
          a4 = make_float4(0.f, 0.f, 0.f, 0.f);
          bprev = b;
        }
        const float wgt = wlds[n - n0];
        const float4 xv = *reinterpret_cast<const float4*>(x + (size_t)n * D + l * 4);
        a4.x = fmaf(xv.x, wgt, a4.x);
        a4.y = fmaf(xv.y, wgt, a4.y);
        a4.z = fmaf(xv.z, wgt, a4.z);
        a4.w = fmaf(xv.w, wgt, a4.w);
      }
      float* o = out + (size_t)bprev * D + l * 4;
      atomicAdd(o + 0, a4.x); atomicAdd(o + 1, a4.y);
      atomicAdd(o + 2, a4.z); atomicAdd(o + 3, a4.w);
    }
  }
}

// ---- finish: out *= 1/Z ----------------------------------------------------
extern "C" __global__ void __launch_bounds__(256)
k_finish(float* __restrict__ out, const float* __restrict__ zacc, int size)
{
  const int i = blockIdx.x * 256 + threadIdx.x;
  if (i < size) out[i] *= (1.0f / *zacc);
}

extern "C" void kernel_launch(void* const* d_in, const int* in_sizes, int n_in,
                              void* d_out, int out_size, void* d_ws, size_t ws_size,
                              hipStream_t stream)
{
  const float* x     = (const float*)d_in[0];
  const int*   batch = (const int*)d_in[1];
  const float* W1 = (const float*)d_in[3];
  const float* b1 = (const float*)d_in[4];
  const float* W2 = (const float*)d_in[5];
  const float* b2 = (const float*)d_in[6];
  const int N = in_sizes[1];

  float* zacc = (float*)d_ws;
  uint4* phi  = (uint4*)((char*)d_ws + 256);            // 64 KB
  uint4* plo  = (uint4*)((char*)d_ws + 256 + 65536);    // 64 KB

  k_init<<<(out_size + 255) / 256, 256, 0, stream>>>((float*)d_out, out_size, zacc);
  k_pack<<<16, 256, 0, stream>>>(W1, phi, plo);

  const int g1 = (N + BM - 1) / BM;
  k_fused2<<<g1, 256, 0, stream>>>(x, batch, phi, plo, b1, W2, b2,
                                   (float*)d_out, zacc, N);

  k_finish<<<(out_size + 255) / 256, 256, 0, stream>>>((float*)d_out, zacc, out_size);
}